// Round 6
// baseline (506.116 us; speedup 1.0000x reference)
//
#include <hip/hip_runtime.h>

#define BATCH 8
#define CCH 256
#define NPOS 4096
#define LOG2E 1.4426950408889634f

typedef __bf16 bf16x8 __attribute__((ext_vector_type(8)));
typedef float f32x4 __attribute__((ext_vector_type(4)));
typedef float f32x16 __attribute__((ext_vector_type(16)));
typedef int i32x4 __attribute__((ext_vector_type(4)));

typedef const __attribute__((address_space(1))) void GAS;
typedef __attribute__((address_space(3))) void LAS;

#define CFENCE() __asm__ volatile("" ::: "memory")
// vmcnt(0), lgkm no-wait(15), exp no-wait(7)
#define WAIT_VM0()   do { CFENCE(); __builtin_amdgcn_s_waitcnt(0x0F70); CFENCE(); } while (0)
// vmcnt(8), lgkm no-wait, exp no-wait
#define WAIT_VM8()   do { CFENCE(); __builtin_amdgcn_s_waitcnt(0x0F78); CFENCE(); } while (0)
// lgkmcnt(0), vmcnt no-wait(63), exp no-wait
#define WAIT_LGKM0() do { CFENCE(); __builtin_amdgcn_s_waitcnt(0xC07F); CFENCE(); } while (0)
#define BAR_RAW() do { CFENCE(); __builtin_amdgcn_s_barrier(); CFENCE(); } while (0)

__device__ __forceinline__ unsigned short f2bf(float f) {
  unsigned u = __builtin_bit_cast(unsigned, f);
  u += 0x7fffu + ((u >> 16) & 1u);
  return (unsigned short)(u >> 16);
}

__device__ __forceinline__ bf16x8 ld_bf8(const unsigned short* p) {
  i32x4 t = *reinterpret_cast<const i32x4*>(p);
  return __builtin_bit_cast(bf16x8, t);
}

__device__ __forceinline__ float fexp2(float x) {
#if __has_builtin(__builtin_amdgcn_exp2f)
  return __builtin_amdgcn_exp2f(x);
#else
  return __builtin_exp2f(x);
#endif
}

// packed f32x2 -> bf16x2 (RNE), one VALU op
__device__ __forceinline__ unsigned cvtpk(float lo, float hi) {
  unsigned r;
  asm("v_cvt_pk_bf16_f32 %0, %1, %2" : "=v"(r) : "v"(lo), "v"(hi));
  return r;
}
// v_permlane32_swap_b32: a' = [a.lo | b.lo], b' = [a.hi | b.hi]
__device__ __forceinline__ void plswap(unsigned& a, unsigned& b) {
  asm("v_permlane32_swap_b32 %0, %1" : "+v"(a), "+v"(b));
}
__device__ __forceinline__ float xmax32(float v) {
  unsigned a = __builtin_bit_cast(unsigned, v), b = a;
  plswap(a, b);
  return fmaxf(__builtin_bit_cast(float, a), __builtin_bit_cast(float, b));
}
__device__ __forceinline__ float xadd32(float v) {
  unsigned a = __builtin_bit_cast(unsigned, v), b = a;
  plswap(a, b);
  return __builtin_bit_cast(float, a) + __builtin_bit_cast(float, b);
}

template <int N> struct IC { static constexpr int v = N; };

// ---------------------------------------------------------------- kernel 1
__global__ void cvt_kernel(const float* __restrict__ Wq,
                           const float* __restrict__ Wk,
                           const float* __restrict__ Wv,
                           unsigned short* __restrict__ dst)
{
  const int idx = blockIdx.x * 256 + threadIdx.x;   // 0..196607
  const float* src = (idx < 65536) ? Wq : ((idx < 131072) ? Wk : Wv);
  dst[idx] = f2bf(src[idx & 65535]);
}

// ---------------------------------------------------------------- kernel 2
__global__ __launch_bounds__(256, 3)
void qkv_kernel(const float* __restrict__ x,
                const unsigned short* __restrict__ Wall,
                const float* __restrict__ bq,
                const float* __restrict__ bk,
                const float* __restrict__ bv,
                unsigned short* __restrict__ qT,
                unsigned short* __restrict__ kT,
                unsigned short* __restrict__ vG)
{
  __shared__ __align__(16) unsigned short xT[64 * 264];   // 33792 B
  __shared__ __align__(16) unsigned short tbuf[64 * 72];  //  9216 B

  const int b   = blockIdx.x;
  const int i0  = blockIdx.y * 64;
  const int tid = threadIdx.x;
  const int w   = tid >> 6;
  const int l   = tid & 63;
  const int n   = l & 15;
  const int q4  = l >> 4;

  {
    const int li = tid & 15;
    const int cg = tid >> 4;
#pragma unroll
    for (int it = 0; it < 16; ++it) {
      const int c = it * 16 + cg;
      f32x4 f = *reinterpret_cast<const f32x4*>(x + ((size_t)b * CCH + c) * NPOS + i0 + li * 4);
#pragma unroll
      for (int e = 0; e < 4; ++e) xT[(li * 4 + e) * 264 + c] = f2bf(f[e]);
    }
  }
  __syncthreads();

  const size_t qbase = (size_t)b * NPOS * CCH;
  bool first = true;

  for (int s = 0; s < 3; ++s) {
    const float* bias = (s == 0) ? bq : (s == 1) ? bk : bv;
    for (int op = 0; op < 4; ++op) {
      const int obase = op * 64;

      const unsigned short* Wp = Wall + s * 65536 + (size_t)(obase + w * 16 + n) * CCH + q4 * 8;
      bf16x8 wfr[8];
#pragma unroll
      for (int kk = 0; kk < 8; ++kk) wfr[kk] = ld_bf8(Wp + kk * 32);

      float bo[4];
#pragma unroll
      for (int r = 0; r < 4; ++r) bo[r] = bias[obase + w * 16 + q4 * 4 + r];

      f32x4 acc[4];
#pragma unroll
      for (int pt = 0; pt < 4; ++pt) {
        acc[pt] = {0.f, 0.f, 0.f, 0.f};
#pragma unroll
        for (int kk = 0; kk < 8; ++kk) {
          bf16x8 bfr = ld_bf8(&xT[(pt * 16 + n) * 264 + kk * 32 + q4 * 8]);
          acc[pt] = __builtin_amdgcn_mfma_f32_16x16x32_bf16(wfr[kk], bfr, acc[pt], 0, 0, 0);
        }
      }

      if (!first) __syncthreads();
      first = false;
      if (s < 2) {
        const float sc = (s == 0) ? LOG2E : 1.0f;
#pragma unroll
        for (int pt = 0; pt < 4; ++pt)
#pragma unroll
          for (int r = 0; r < 4; ++r)
            tbuf[(pt * 16 + n) * 72 + w * 16 + q4 * 4 + r] = f2bf((acc[pt][r] + bo[r]) * sc);
      } else {
#pragma unroll
        for (int pt = 0; pt < 4; ++pt)
#pragma unroll
          for (int r = 0; r < 4; ++r)
            tbuf[(w * 16 + q4 * 4 + r) * 72 + pt * 16 + n] = f2bf(acc[pt][r] + bo[r]);
      }
      __syncthreads();

      if (s < 2) {
        unsigned short* dst = (s == 0 ? qT : kT) + qbase;
#pragma unroll
        for (int it2 = 0; it2 < 2; ++it2) {
          const int idx = it2 * 256 + tid;
          const int pos = idx >> 3, ow = (idx & 7) * 8;
          i32x4 d = *reinterpret_cast<const i32x4*>(&tbuf[pos * 72 + ow]);
          *reinterpret_cast<i32x4*>(&dst[(size_t)(i0 + pos) * CCH + obase + ow]) = d;
        }
      } else {
#pragma unroll
        for (int it2 = 0; it2 < 2; ++it2) {
          const int idx = it2 * 256 + tid;
          const int o = idx >> 3, pw2 = (idx & 7) * 8;
          i32x4 d = *reinterpret_cast<const i32x4*>(&tbuf[o * 72 + pw2]);
          *reinterpret_cast<i32x4*>(&vG[qbase + (size_t)(obase + o) * NPOS + i0 + pw2]) = d;
        }
      }
    }
  }
}

// ---------------------------------------------------------------- kernel 3
// Flash attention, 32x32x16 MFMA, S^T = K*Q (P-row per lane column).
// IDENTICAL to the r4 passing kernel except __launch_bounds__(256, 1):
// r4 spilled ~6MB at VGPR_Count=128 under (256,2) — relax the declared
// occupancy floor so the allocator can use the unified file (up to 512);
// actual usage ~200 keeps hardware occupancy at 2 blocks/CU.
__global__ __launch_bounds__(256, 1)
void attn_kernel(const unsigned short* __restrict__ qT,
                 const unsigned short* __restrict__ kT,
                 const unsigned short* __restrict__ vG,
                 const float* __restrict__ x,
                 const float* __restrict__ gamma,
                 float* __restrict__ out)
{
  __shared__ __align__(16) unsigned short kbuf[2][64 * 256];  // 64 KB, granule-XOR swizzled rows
  __shared__ __align__(16) unsigned pfrag[4][64][8];          //  8 KB assembled P-frags
  __shared__ __align__(8)  float stats[4][32][2];             //  1 KB (m_w, s_w)

  const int b   = blockIdx.x;
  const int i0  = blockIdx.y * 64;
  const int tid = threadIdx.x;
  const int w   = tid >> 6;
  const int l   = tid & 63;
  const int l31 = l & 31;
  const int g0  = l >> 5;
  const int ih  = w >> 1;     // i-half
  const int jh  = w & 1;      // j-half
  const int pw  = w ^ 1;      // partner wave (other j-half, same i-half)
  const int sw4 = (l >> 2) & 1;  // pfrag slot swizzle bit

  const unsigned short* qTb = qT + (size_t)b * NPOS * CCH;
  const unsigned short* kTb = kT + (size_t)b * NPOS * CCH;
  const unsigned short* vb  = vG + (size_t)b * NPOS * CCH;

  // Q register-resident: B-frag, i = i0 + ih*32 + l31, k(ch) = kt*16 + g0*8 + e
  bf16x8 qf[16];
  {
    const unsigned short* qrow = qTb + (size_t)(i0 + ih * 32 + l31) * CCH + g0 * 8;
#pragma unroll
    for (int kt = 0; kt < 16; ++kt) qf[kt] = ld_bf8(qrow + kt * 16);
  }

  // K LDS A-frag bases: row = jh*32+l31, phys granule = (g0+2q)^(row&7); kt>>2 -> +128B imm
  unsigned kaddr[4];
#pragma unroll
  for (int q = 0; q < 4; ++q)
    kaddr[q] = (unsigned)((jh * 32 + l31) * 512 + (((g0 + 2 * q) ^ (l & 7)) << 4));

  // K DMA source byte-offsets (pre-swizzled global, linear LDS dest)
  unsigned kdoff[8];
#pragma unroll
  for (int it = 0; it < 8; ++it) {
    const int j  = 2 * (w * 8 + it) + g0;
    const int gg = l31 ^ (j & 7);
    kdoff[it] = (unsigned)(j * (CCH * 2) + gg * 16);
  }

  // V byte-offsets rel vb, +128/iter. Chunk slots ordered own-jh first.
  unsigned voff[4];
#pragma unroll
  for (int ct = 0; ct < 4; ++ct)
    voff[ct] = (unsigned)(((jh * 128 + ct * 32 + l31) * NPOS + g0 * 8) * 2);
  const unsigned kcho0 = (unsigned)(jh * 64);         // own j-chunk pair
  const unsigned kcho1 = (unsigned)((jh ^ 1) * 64);   // partner j-chunk pair

  // prologue: stage K[0]
#pragma unroll
  for (int it = 0; it < 8; ++it) {
    const unsigned short* src = (const unsigned short*)((const char*)kTb + kdoff[it]);
    unsigned short* dst = &kbuf[0][(w * 8 + it) * 512];
    __builtin_amdgcn_global_load_lds((GAS*)src, (LAS*)dst, 16, 0, 0);
  }

  f32x16 O[4];
#pragma unroll
  for (int ct = 0; ct < 4; ++ct)
#pragma unroll
    for (int r = 0; r < 16; ++r) O[ct][r] = 0.f;
  float mcur = 64.f;     // lagging exp2-domain max (init bounds exp2 <= 2^77)
  float lrow = 0.f;

  auto step = [&](int jt, auto BUFTAG) {
    constexpr int BUF = decltype(BUFTAG)::v;

    WAIT_VM0();       // drain K[jt] DMA (everything else already consumed)
    BAR_RAW();        // K[jt] visible to all waves

    // S^T = K * Q  (A = K from LDS, B = Q regs). col = i (l31), rows = j-local
    f32x16 sacc;
#pragma unroll
    for (int r = 0; r < 16; ++r) sacc[r] = 0.f;
#pragma unroll
    for (int kt = 0; kt < 16; ++kt) {
      const unsigned short* kp = (const unsigned short*)(
          (const char*)(&kbuf[BUF][0]) + kaddr[kt & 3] + (kt >> 2) * 128);
      sacc = __builtin_amdgcn_mfma_f32_32x32x16_bf16(ld_bf8(kp), qf[kt], sacc, 0, 0, 0);
    }

    // V chunk A loads (ct 0,1) — softmax + pack below cover the latency
    i32x4 vra[8];
#pragma unroll
    for (int ct = 0; ct < 2; ++ct) {
      const char* vbase = (const char*)vb + voff[ct];
      vra[ct * 4 + 0] = *(const i32x4*)(vbase + kcho0);
      vra[ct * 4 + 1] = *(const i32x4*)(vbase + kcho0 + 32);
      vra[ct * 4 + 2] = *(const i32x4*)(vbase + kcho1);
      vra[ct * 4 + 3] = *(const i32x4*)(vbase + kcho1 + 32);
    }

    // in-lane partial max over this wave's 32 j (16 in-lane + lane^32 swap)
    float mw;
    {
      float a0 = fmaxf(sacc[0], sacc[1]),   a1 = fmaxf(sacc[2], sacc[3]);
      float a2 = fmaxf(sacc[4], sacc[5]),   a3 = fmaxf(sacc[6], sacc[7]);
      float a4 = fmaxf(sacc[8], sacc[9]),   a5 = fmaxf(sacc[10], sacc[11]);
      float a6 = fmaxf(sacc[12], sacc[13]), a7 = fmaxf(sacc[14], sacc[15]);
      a0 = fmaxf(a0, a1); a2 = fmaxf(a2, a3); a4 = fmaxf(a4, a5); a6 = fmaxf(a6, a7);
      mw = xmax32(fmaxf(fmaxf(a0, a2), fmaxf(a4, a6)));
    }

    // P = exp2(S - mcur), in place (lagging scale; independent of max tree)
#pragma unroll
    for (int r = 0; r < 16; ++r) sacc[r] = fexp2(sacc[r] - mcur);

    float sw;
    {
      float s0 = (sacc[0] + sacc[1]) + (sacc[2] + sacc[3]);
      float s1 = (sacc[4] + sacc[5]) + (sacc[6] + sacc[7]);
      float s2 = (sacc[8] + sacc[9]) + (sacc[10] + sacc[11]);
      float s3 = (sacc[12] + sacc[13]) + (sacc[14] + sacc[15]);
      sw = xadd32((s0 + s1) + (s2 + s3));
    }

    // pack P -> PV B-frags in registers: 8 cvt_pk + 4 permlane32_swap
    unsigned U0 = cvtpk(sacc[0], sacc[1]),   U1 = cvtpk(sacc[2], sacc[3]);
    unsigned U2 = cvtpk(sacc[4], sacc[5]),   U3 = cvtpk(sacc[6], sacc[7]);
    unsigned U4 = cvtpk(sacc[8], sacc[9]),   U5 = cvtpk(sacc[10], sacc[11]);
    unsigned U6 = cvtpk(sacc[12], sacc[13]), U7 = cvtpk(sacc[14], sacc[15]);
    unsigned s0a = U0, s0b = U2; plswap(s0a, s0b);
    unsigned s1a = U1, s1b = U3; plswap(s1a, s1b);
    unsigned s2a = U4, s2b = U6; plswap(s2a, s2b);
    unsigned s3a = U5, s3b = U7; plswap(s3a, s3b);
    i32x4 ownA = { (int)s0a, (int)s1a, (int)s0b, (int)s1b };  // own j-chunk 0
    i32x4 ownB = { (int)s2a, (int)s3a, (int)s2b, (int)s3b };  // own j-chunk 1
    // pfrag slot XOR-swizzle: lanes l, l+4 (same bank group) use opposite slots
    *(i32x4*)&pfrag[w][l][sw4 ? 4 : 0] = ownA;
    *(i32x4*)&pfrag[w][l][sw4 ? 0 : 4] = ownB;
    if (!g0) { stats[w][l31][0] = mw; stats[w][l31][1] = sw; }

    // prefetch K[jt+1] DMA into other buffer
    {
      const unsigned koffn = (unsigned)(((jt + 1) & 63) * 32768);
#pragma unroll
      for (int it = 0; it < 8; ++it) {
        const unsigned short* src =
            (const unsigned short*)((const char*)kTb + (kdoff[it] + koffn));
        unsigned short* dst = &kbuf[BUF ^ 1][(w * 8 + it) * 512];
        __builtin_amdgcn_global_load_lds((GAS*)src, (LAS*)dst, 16, 0, 0);
      }
    }

    WAIT_LGKM0();     // my pfrag/stat writes landed
    BAR_RAW();        // partner frags + stats visible; K' DMA stays in flight

    i32x4 oppA = *(const i32x4*)&pfrag[pw][l][sw4 ? 4 : 0];
    i32x4 oppB = *(const i32x4*)&pfrag[pw][l][sw4 ? 0 : 4];
    const float mp = stats[pw][l31][0];
    const float sp = stats[pw][l31][1];

    const bf16x8 FB0 = __builtin_bit_cast(bf16x8, ownA);
    const bf16x8 FB1 = __builtin_bit_cast(bf16x8, ownB);
    const bf16x8 FB2 = __builtin_bit_cast(bf16x8, oppA);
    const bf16x8 FB3 = __builtin_bit_cast(bf16x8, oppB);

    WAIT_VM8();       // vra ready (8 newest = K' DMA, stays in flight)
    // PV chunk A: ct 0,1
#pragma unroll
    for (int ct = 0; ct < 2; ++ct) {
      O[ct] = __builtin_amdgcn_mfma_f32_32x32x16_bf16(
          __builtin_bit_cast(bf16x8, vra[ct * 4 + 0]), FB0, O[ct], 0, 0, 0);
      O[ct] = __builtin_amdgcn_mfma_f32_32x32x16_bf16(
          __builtin_bit_cast(bf16x8, vra[ct * 4 + 1]), FB1, O[ct], 0, 0, 0);
      O[ct] = __builtin_amdgcn_mfma_f32_32x32x16_bf16(
          __builtin_bit_cast(bf16x8, vra[ct * 4 + 2]), FB2, O[ct], 0, 0, 0);
      O[ct] = __builtin_amdgcn_mfma_f32_32x32x16_bf16(
          __builtin_bit_cast(bf16x8, vra[ct * 4 + 3]), FB3, O[ct], 0, 0, 0);
    }

    // V chunk B loads (ct 2,3) — reuse the 32 VGPRs freed by PV-A
    i32x4 vrb[8];
#pragma unroll
    for (int ct = 0; ct < 2; ++ct) {
      const char* vbase = (const char*)vb + voff[2 + ct];
      vrb[ct * 4 + 0] = *(const i32x4*)(vbase + kcho0);
      vrb[ct * 4 + 1] = *(const i32x4*)(vbase + kcho0 + 32);
      vrb[ct * 4 + 2] = *(const i32x4*)(vbase + kcho1);
      vrb[ct * 4 + 3] = *(const i32x4*)(vbase + kcho1 + 32);
    }
    // PV chunk B: ct 2,3 (compiler waits vmcnt(0); K' nearly landed by now)
#pragma unroll
    for (int ct = 0; ct < 2; ++ct) {
      O[2 + ct] = __builtin_amdgcn_mfma_f32_32x32x16_bf16(
          __builtin_bit_cast(bf16x8, vrb[ct * 4 + 0]), FB0, O[2 + ct], 0, 0, 0);
      O[2 + ct] = __builtin_amdgcn_mfma_f32_32x32x16_bf16(
          __builtin_bit_cast(bf16x8, vrb[ct * 4 + 1]), FB1, O[2 + ct], 0, 0, 0);
      O[2 + ct] = __builtin_amdgcn_mfma_f32_32x32x16_bf16(
          __builtin_bit_cast(bf16x8, vrb[ct * 4 + 2]), FB2, O[2 + ct], 0, 0, 0);
      O[2 + ct] = __builtin_amdgcn_mfma_f32_32x32x16_bf16(
          __builtin_bit_cast(bf16x8, vrb[ct * 4 + 3]), FB3, O[2 + ct], 0, 0, 0);
    }

    // stats combine + deferred rescale (skipped when no row max grew by >8)
    const float mt = fmaxf(mw, mp);
    lrow += sw + sp;
    const int upd = mt > mcur + 8.f;
    if (__any(upd)) {
      const float mn = upd ? mt : mcur;
      const float al = fexp2(mcur - mn);
      mcur = mn;
      lrow *= al;
#pragma unroll
      for (int ct = 0; ct < 4; ++ct)
#pragma unroll
        for (int r = 0; r < 16; ++r) O[ct][r] *= al;
    }

#pragma unroll
    for (int ct = 0; ct < 4; ++ct) voff[ct] += 128;
  };

  for (int jt2 = 0; jt2 < 32; ++jt2) {
    step(2 * jt2,     IC<0>{});
    step(2 * jt2 + 1, IC<1>{});
  }

  // epilogue: out = x + gamma * O / lrow  (all state lane-local)
  const float sc = gamma[0] / lrow;
  const int ipos = i0 + ih * 32 + l31;
#pragma unroll
  for (int ct = 0; ct < 4; ++ct) {
#pragma unroll
    for (int r = 0; r < 16; ++r) {
      const int c = jh * 128 + ct * 32 + (r & 3) + 8 * (r >> 2) + 4 * g0;
      const size_t idx = ((size_t)(b * CCH + c)) * NPOS + ipos;
      out[idx] = x[idx] + sc * O[ct][r];
    }
  }
}

// ---------------------------------------------------------------- launch
extern "C" void kernel_launch(void* const* d_in, const int* in_sizes, int n_in,
                              void* d_out, int out_size, void* d_ws, size_t ws_size,
                              hipStream_t stream)
{
  const float* x     = (const float*)d_in[0];
  const float* Wq    = (const float*)d_in[1];
  const float* bq    = (const float*)d_in[2];
  const float* Wk    = (const float*)d_in[3];
  const float* bk    = (const float*)d_in[4];
  const float* Wv    = (const float*)d_in[5];
  const float* bv    = (const float*)d_in[6];
  const float* gamma = (const float*)d_in[7];
  float* out = (float*)d_out;

  unsigned short* ws   = (unsigned short*)d_ws;
  unsigned short* Wall = ws;                                  // 3 x 65536 bf16
  unsigned short* qT   = ws + 196608;                         // (B,N,C) bf16, pre-scaled log2e
  unsigned short* kT   = qT + (size_t)BATCH * NPOS * CCH;     // (B,N,C) bf16
  unsigned short* vG   = kT + (size_t)BATCH * NPOS * CCH;     // (B,C,N) bf16

  cvt_kernel<<<768, 256, 0, stream>>>(Wq, Wk, Wv, Wall);
  qkv_kernel<<<dim3(8, 64), 256, 0, stream>>>(x, Wall, bq, bk, bv, qT, kT, vG);
  attn_kernel<<<dim3(8, 64), 256, 0, stream>>>(qT, kT, vG, x, gamma, out);
}

// Round 7
// 301.512 us; speedup vs baseline: 1.6786x; 1.6786x over previous
//
#include <hip/hip_runtime.h>

#define BATCH 8
#define CCH 256
#define NPOS 4096
#define LOG2E 1.4426950408889634f

typedef __bf16 bf16x8 __attribute__((ext_vector_type(8)));
typedef float f32x4 __attribute__((ext_vector_type(4)));
typedef int i32x4 __attribute__((ext_vector_type(4)));
typedef int i32x2 __attribute__((ext_vector_type(2)));

typedef const __attribute__((address_space(1))) void GAS;
typedef __attribute__((address_space(3))) void LAS;

#define CFENCE() __asm__ volatile("" ::: "memory")
// vmcnt(8), lgkmcnt no-wait(15), expcnt no-wait(7): (15<<8)|(7<<4)|8
#define WAIT_VM8()  do { CFENCE(); __builtin_amdgcn_s_waitcnt(0x0F78); CFENCE(); } while (0)
// lgkmcnt(0), vmcnt no-wait(63: low4=15,hi2=3), expcnt no-wait
#define WAIT_LGKM0() do { CFENCE(); __builtin_amdgcn_s_waitcnt(0xC07F); CFENCE(); } while (0)
#define BAR_RAW() do { CFENCE(); __builtin_amdgcn_s_barrier(); CFENCE(); } while (0)

__device__ __forceinline__ unsigned short f2bf(float f) {
  unsigned u = __builtin_bit_cast(unsigned, f);
  u += 0x7fffu + ((u >> 16) & 1u);
  return (unsigned short)(u >> 16);
}

__device__ __forceinline__ bf16x8 ld_bf8(const unsigned short* p) {
  i32x4 t = *reinterpret_cast<const i32x4*>(p);
  return __builtin_bit_cast(bf16x8, t);
}

__device__ __forceinline__ float fexp2(float x) {
#if __has_builtin(__builtin_amdgcn_exp2f)
  return __builtin_amdgcn_exp2f(x);
#else
  return __builtin_exp2f(x);
#endif
}

// packed f32x2 -> bf16x2 (RNE), one VALU op
__device__ __forceinline__ unsigned cvtpk(float lo, float hi) {
  unsigned r;
  asm("v_cvt_pk_bf16_f32 %0, %1, %2" : "=v"(r) : "v"(lo), "v"(hi));
  return r;
}

// ---------------------------------------------------------------- kernel 1
__global__ void cvt_kernel(const float* __restrict__ Wq,
                           const float* __restrict__ Wk,
                           const float* __restrict__ Wv,
                           unsigned short* __restrict__ dst)
{
  const int idx = blockIdx.x * 256 + threadIdx.x;   // 0..196607
  const float* src = (idx < 65536) ? Wq : ((idx < 131072) ? Wk : Wv);
  dst[idx] = f2bf(src[idx & 65535]);
}

// ---------------------------------------------------------------- kernel 2
// Single pass per (b, pos-tile): x staged once (coalesced), 3 selectors x
// 4 o-strips from register-resident W. q pre-scaled by log2(e).
__global__ __launch_bounds__(256, 3)
void qkv_kernel(const float* __restrict__ x,
                const unsigned short* __restrict__ Wall,
                const float* __restrict__ bq,
                const float* __restrict__ bk,
                const float* __restrict__ bv,
                unsigned short* __restrict__ qT,
                unsigned short* __restrict__ kT,
                unsigned short* __restrict__ vG)
{
  __shared__ __align__(16) unsigned short xT[64 * 264];   // 33792 B
  __shared__ __align__(16) unsigned short tbuf[64 * 72];  //  9216 B

  const int b   = blockIdx.x;
  const int i0  = blockIdx.y * 64;
  const int tid = threadIdx.x;
  const int w   = tid >> 6;
  const int l   = tid & 63;
  const int n   = l & 15;
  const int q4  = l >> 4;

  {
    const int li = tid & 15;
    const int cg = tid >> 4;
#pragma unroll
    for (int it = 0; it < 16; ++it) {
      const int c = it * 16 + cg;
      f32x4 f = *reinterpret_cast<const f32x4*>(x + ((size_t)b * CCH + c) * NPOS + i0 + li * 4);
#pragma unroll
      for (int e = 0; e < 4; ++e) xT[(li * 4 + e) * 264 + c] = f2bf(f[e]);
    }
  }
  __syncthreads();

  const size_t qbase = (size_t)b * NPOS * CCH;
  bool first = true;

  for (int s = 0; s < 3; ++s) {
    const float* bias = (s == 0) ? bq : (s == 1) ? bk : bv;
    for (int op = 0; op < 4; ++op) {
      const int obase = op * 64;

      const unsigned short* Wp = Wall + s * 65536 + (size_t)(obase + w * 16 + n) * CCH + q4 * 8;
      bf16x8 wfr[8];
#pragma unroll
      for (int kk = 0; kk < 8; ++kk) wfr[kk] = ld_bf8(Wp + kk * 32);

      float bo[4];
#pragma unroll
      for (int r = 0; r < 4; ++r) bo[r] = bias[obase + w * 16 + q4 * 4 + r];

      f32x4 acc[4];
#pragma unroll
      for (int pt = 0; pt < 4; ++pt) {
        acc[pt] = {0.f, 0.f, 0.f, 0.f};
#pragma unroll
        for (int kk = 0; kk < 8; ++kk) {
          bf16x8 bfr = ld_bf8(&xT[(pt * 16 + n) * 264 + kk * 32 + q4 * 8]);
          acc[pt] = __builtin_amdgcn_mfma_f32_16x16x32_bf16(wfr[kk], bfr, acc[pt], 0, 0, 0);
        }
      }

      if (!first) __syncthreads();
      first = false;
      if (s < 2) {
        const float sc = (s == 0) ? LOG2E : 1.0f;
#pragma unroll
        for (int pt = 0; pt < 4; ++pt)
#pragma unroll
          for (int r = 0; r < 4; ++r)
            tbuf[(pt * 16 + n) * 72 + w * 16 + q4 * 4 + r] = f2bf((acc[pt][r] + bo[r]) * sc);
      } else {
#pragma unroll
        for (int pt = 0; pt < 4; ++pt)
#pragma unroll
          for (int r = 0; r < 4; ++r)
            tbuf[(w * 16 + q4 * 4 + r) * 72 + pt * 16 + n] = f2bf(acc[pt][r] + bo[r]);
      }
      __syncthreads();

      if (s < 2) {
        unsigned short* dst = (s == 0 ? qT : kT) + qbase;
#pragma unroll
        for (int it2 = 0; it2 < 2; ++it2) {
          const int idx = it2 * 256 + tid;
          const int pos = idx >> 3, ow = (idx & 7) * 8;
          i32x4 d = *reinterpret_cast<const i32x4*>(&tbuf[pos * 72 + ow]);
          *reinterpret_cast<i32x4*>(&dst[(size_t)(i0 + pos) * CCH + obase + ow]) = d;
        }
      } else {
#pragma unroll
        for (int it2 = 0; it2 < 2; ++it2) {
          const int idx = it2 * 256 + tid;
          const int o = idx >> 3, pw2 = (idx & 7) * 8;
          i32x4 d = *reinterpret_cast<const i32x4*>(&tbuf[o * 72 + pw2]);
          *reinterpret_cast<i32x4*>(&vG[qbase + (size_t)(obase + o) * NPOS + i0 + pw2]) = d;
        }
      }
    }
  }
}

// ---------------------------------------------------------------- kernel 3
// Flash attention = r1 structure + S^T operand swap:
//  - QK^T computed as mfma(K_frag, Q_frag) -> lane holds S^T[j-set][i=lane&15]
//    (K/Q per-lane addressing BYTE-IDENTICAL to r1; only intrinsic arg order)
//  - softmax lane-local: 15-op tree + shfl_xor(16,32); m/l = 2 scalars
//  - P store: 8 cvt_pk + 4 ds_write_b64 (was 16 scalar b16 = the bank-conflict
//    source); pbuf stays [i][j] with phys granule = logical ^ (row&7)
//  - PV reads / MFMAs / epilogue / DMA / barriers: byte-identical to r1
__global__ __launch_bounds__(256, 2)
void attn_kernel(const unsigned short* __restrict__ qT,
                 const unsigned short* __restrict__ kT,
                 const unsigned short* __restrict__ vG,
                 const float* __restrict__ x,
                 const float* __restrict__ gamma,
                 float* __restrict__ out)
{
  __shared__ __align__(16) unsigned short kbuf[2][64 * 256];  // 2 x 32768 B, swizzled
  __shared__ __align__(16) unsigned short pbuf[64 * 64];      //  8192 B, swizzled
  __shared__ float stat_lds[64];

  const int b   = blockIdx.x;
  const int i0  = blockIdx.y * 64;
  const int tid = threadIdx.x;
  const int w   = tid >> 6;
  const int l   = tid & 63;
  const int n   = l & 15;
  const int q4  = l >> 4;
  const int nsw = n & 7;

  const unsigned short* qTb = qT + (size_t)b * NPOS * CCH;
  const unsigned short* kTb = kT + (size_t)b * NPOS * CCH;
  const unsigned short* vb  = vG + (size_t)b * NPOS * CCH;

  // Q fragments register-resident (pre-scaled by log2e). Used as B operand:
  // lane holds Q[i = i0 + w*16 + n][ch = kk*32 + q4*8 + e]
  bf16x8 afr[8];
  {
    const unsigned short* qrow = qTb + (size_t)(i0 + w * 16 + n) * CCH + q4 * 8;
#pragma unroll
    for (int kk = 0; kk < 8; ++kk)
      afr[kk] = ld_bf8(qrow + kk * 32);
  }

  // stage K[0]: wave issues 8 DMA loads, instruction t covers local rows 2t,2t+1.
  // LDS granule (j,gp) holds logical granule g = gp ^ (j&7)  (bank-spread swizzle).
  {
#pragma unroll
    for (int it = 0; it < 8; ++it) {
      const int t = w * 8 + it;
      const int j = 2 * t + (l >> 5);
      const int gp = l & 31;
      const int g  = gp ^ (j & 7);
      const unsigned short* src = kTb + (size_t)j * CCH + g * 8;
      unsigned short* dst = &kbuf[0][t * 512];    // wave-uniform base
      __builtin_amdgcn_global_load_lds((GAS*)src, (LAS*)dst, 16, 0, 0);
    }
  }

  f32x4 O[16];   // [ct*4+it]: c in [w*64+ct*16,+16), i in [it*16,+16)
#pragma unroll
  for (int t = 0; t < 16; ++t) O[t] = {0.f, 0.f, 0.f, 0.f};
  float mrow = -1e30f;   // per-lane state for i = i0 + w*16 + n
  float lrow = 0.f;

  for (int jt = 0; jt < 64; ++jt) {
    const int j0 = jt * 64;
    const unsigned short* kb = kbuf[jt & 1];

    // prefetch V[jt] into registers (always the 8 NEWEST vmem ops)
    i32x4 vreg[8];
#pragma unroll
    for (int ct = 0; ct < 4; ++ct) {
      const unsigned short* vp = vb + (size_t)(w * 64 + ct * 16 + n) * NPOS + j0 + q4 * 8;
      vreg[ct * 2]     = *reinterpret_cast<const i32x4*>(vp);
      vreg[ct * 2 + 1] = *reinterpret_cast<const i32x4*>(vp + 32);
    }

    WAIT_VM8();     // drain everything older than V[jt] => K[jt] DMA complete
    BAR_RAW();      // all waves' K[jt] in LDS; pbuf/stat free (readers done pre-barrier)

    // S^T = K * Q: A = K (LDS, swizzled reads identical to r1), B = Q regs.
    // D: lane holds S^T[j = nt*16 + q4*4 + r][i = n]
    f32x4 sacc[4];
#pragma unroll
    for (int nt = 0; nt < 4; ++nt) {
      const unsigned short* krow = kb + (nt * 16 + n) * 256;
      sacc[nt] = {0.f, 0.f, 0.f, 0.f};
#pragma unroll
      for (int kk = 0; kk < 8; ++kk) {
        const int gp = (kk * 4 + q4) ^ nsw;
        bf16x8 bfr = ld_bf8(krow + gp * 8);
        sacc[nt] = __builtin_amdgcn_mfma_f32_16x16x32_bf16(bfr, afr[kk], sacc[nt], 0, 0, 0);
      }
    }

    // online softmax, lane-local (i = n); reduce over 16 in-lane j + q4 groups
    float tm;
    {
      float a0 = fmaxf(fmaxf(sacc[0][0], sacc[0][1]), fmaxf(sacc[0][2], sacc[0][3]));
      float a1 = fmaxf(fmaxf(sacc[1][0], sacc[1][1]), fmaxf(sacc[1][2], sacc[1][3]));
      float a2 = fmaxf(fmaxf(sacc[2][0], sacc[2][1]), fmaxf(sacc[2][2], sacc[2][3]));
      float a3 = fmaxf(fmaxf(sacc[3][0], sacc[3][1]), fmaxf(sacc[3][2], sacc[3][3]));
      tm = fmaxf(fmaxf(a0, a1), fmaxf(a2, a3));
      tm = fmaxf(tm, __shfl_xor(tm, 16));
      tm = fmaxf(tm, __shfl_xor(tm, 32));
    }
    const float mnew = fmaxf(mrow, tm);
    const float alpha = fexp2(mrow - mnew);
    float s = 0.f;
#pragma unroll
    for (int nt = 0; nt < 4; ++nt) {
#pragma unroll
      for (int r = 0; r < 4; ++r) {
        const float p = fexp2(sacc[nt][r] - mnew);
        sacc[nt][r] = p;
        s += p;
      }
    }
    s += __shfl_xor(s, 16);
    s += __shfl_xor(s, 32);
    lrow = lrow * alpha + s;
    mrow = mnew;

    if (q4 == 0) stat_lds[w * 16 + n] = alpha;

    // P -> pbuf row i = w*16+n: j pairs packed, 4 x ds_write_b64.
    // u16 slot j, granule = j/8, phys = granule ^ (row&7) = granule ^ nsw.
    {
      const int rowb = (w * 16 + n) * 64;
#pragma unroll
      for (int nt = 0; nt < 4; ++nt) {
        const unsigned lo = cvtpk(sacc[nt][0], sacc[nt][1]);
        const unsigned hi = cvtpk(sacc[nt][2], sacc[nt][3]);
        const int pg = (2 * nt + (q4 >> 1)) ^ nsw;
        i32x2 dv = { (int)lo, (int)hi };
        *reinterpret_cast<i32x2*>(&pbuf[rowb + pg * 8 + (q4 & 1) * 4]) = dv;
      }
    }

    // prefetch K[jt+1] DMA into other buffer (UNCONDITIONAL, wrapped: keeps
    // compiler's V-use wait at vmcnt(8) instead of vmcnt(0))
    {
      const int j0n = ((jt + 1) & 63) * 64;
      unsigned short* bufn = kbuf[(jt + 1) & 1];
#pragma unroll
      for (int it = 0; it < 8; ++it) {
        const int t = w * 8 + it;
        const int j = 2 * t + (l >> 5);
        const int gp = l & 31;
        const int g  = gp ^ (j & 7);
        const unsigned short* src = kTb + (size_t)(j0n + j) * CCH + g * 8;
        unsigned short* dst = &bufn[t * 512];
        __builtin_amdgcn_global_load_lds((GAS*)src, (LAS*)dst, 16, 0, 0);
      }
    }

    WAIT_LGKM0();   // my P/alpha writes landed
    BAR_RAW();      // P + alpha visible to all; K' DMA still in flight

    // rescale O by alpha[i]
#pragma unroll
    for (int it = 0; it < 4; ++it) {
      const float al = stat_lds[it * 16 + n];
#pragma unroll
      for (int ct = 0; ct < 4; ++ct) {
        f32x4& o = O[ct * 4 + it];
        o[0] *= al; o[1] *= al; o[2] *= al; o[3] *= al;
      }
    }

    // PV: V from registers, P from swizzled LDS (identical to r1)
    bf16x8 pf[8];
#pragma unroll
    for (int it = 0; it < 4; ++it) {
      const int rowb = (it * 16 + n) * 64;
      pf[it * 2 + 0] = ld_bf8(&pbuf[rowb + ((q4 ^ nsw) << 3)]);
      pf[it * 2 + 1] = ld_bf8(&pbuf[rowb + (((4 + q4) ^ nsw) << 3)]);
    }
#pragma unroll
    for (int ct = 0; ct < 4; ++ct) {
      bf16x8 vf0 = __builtin_bit_cast(bf16x8, vreg[ct * 2]);
      bf16x8 vf1 = __builtin_bit_cast(bf16x8, vreg[ct * 2 + 1]);
#pragma unroll
      for (int it = 0; it < 4; ++it) {
        O[ct * 4 + it] = __builtin_amdgcn_mfma_f32_16x16x32_bf16(vf0, pf[it * 2 + 0], O[ct * 4 + it], 0, 0, 0);
        O[ct * 4 + it] = __builtin_amdgcn_mfma_f32_16x16x32_bf16(vf1, pf[it * 2 + 1], O[ct * 4 + it], 0, 0, 0);
      }
    }
  }

  // epilogue: y = x + gamma * O / l   (full-drain syncthreads fine here)
  __syncthreads();
  if (q4 == 0) stat_lds[w * 16 + n] = lrow;
  __syncthreads();

  const float g = gamma[0];
#pragma unroll
  for (int it = 0; it < 4; ++it) {
    const float sc = g / stat_lds[it * 16 + n];
    const int ipos = i0 + it * 16 + n;
#pragma unroll
    for (int ct = 0; ct < 4; ++ct) {
#pragma unroll
      for (int r = 0; r < 4; ++r) {
        const int c = w * 64 + ct * 16 + q4 * 4 + r;
        const size_t idx = ((size_t)(b * CCH + c)) * NPOS + ipos;
        out[idx] = x[idx] + sc * O[ct * 4 + it][r];
      }
    }
  }
}

// ---------------------------------------------------------------- launch
extern "C" void kernel_launch(void* const* d_in, const int* in_sizes, int n_in,
                              void* d_out, int out_size, void* d_ws, size_t ws_size,
                              hipStream_t stream)
{
  const float* x     = (const float*)d_in[0];
  const float* Wq    = (const float*)d_in[1];
  const float* bq    = (const float*)d_in[2];
  const float* Wk    = (const float*)d_in[3];
  const float* bk    = (const float*)d_in[4];
  const float* Wv    = (const float*)d_in[5];
  const float* bv    = (const float*)d_in[6];
  const float* gamma = (const float*)d_in[7];
  float* out = (float*)d_out;

  unsigned short* ws   = (unsigned short*)d_ws;
  unsigned short* Wall = ws;                                  // 3 x 65536 bf16
  unsigned short* qT   = ws + 196608;                         // (B,N,C) bf16, pre-scaled log2e
  unsigned short* kT   = qT + (size_t)BATCH * NPOS * CCH;     // (B,N,C) bf16
  unsigned short* vG   = kT + (size_t)BATCH * NPOS * CCH;     // (B,C,N) bf16

  cvt_kernel<<<768, 256, 0, stream>>>(Wq, Wk, Wv, Wall);
  qkv_kernel<<<dim3(8, 64), 256, 0, stream>>>(x, Wall, bq, bk, bv, qT, kT, vG);
  attn_kernel<<<dim3(8, 64), 256, 0, stream>>>(qT, kT, vG, x, gamma, out);
}

// Round 9
// 296.120 us; speedup vs baseline: 1.7092x; 1.0182x over previous
//
#include <hip/hip_runtime.h>

#define BATCH 8
#define CCH 256
#define NPOS 4096
#define LOG2E 1.4426950408889634f

typedef __bf16 bf16x8 __attribute__((ext_vector_type(8)));
typedef float f32x4 __attribute__((ext_vector_type(4)));
typedef int i32x4 __attribute__((ext_vector_type(4)));
typedef int i32x2 __attribute__((ext_vector_type(2)));

typedef const __attribute__((address_space(1))) void GAS;
typedef __attribute__((address_space(3))) void LAS;

#define CFENCE() __asm__ volatile("" ::: "memory")
// vmcnt(8), lgkmcnt no-wait(15), expcnt no-wait(7): (15<<8)|(7<<4)|8
#define WAIT_VM8()  do { CFENCE(); __builtin_amdgcn_s_waitcnt(0x0F78); CFENCE(); } while (0)
// lgkmcnt(0), vmcnt no-wait(63: low4=15,hi2=3), expcnt no-wait
#define WAIT_LGKM0() do { CFENCE(); __builtin_amdgcn_s_waitcnt(0xC07F); CFENCE(); } while (0)
#define BAR_RAW() do { CFENCE(); __builtin_amdgcn_s_barrier(); CFENCE(); } while (0)

__device__ __forceinline__ unsigned short f2bf(float f) {
  unsigned u = __builtin_bit_cast(unsigned, f);
  u += 0x7fffu + ((u >> 16) & 1u);
  return (unsigned short)(u >> 16);
}

__device__ __forceinline__ bf16x8 ld_bf8(const unsigned short* p) {
  i32x4 t = *reinterpret_cast<const i32x4*>(p);
  return __builtin_bit_cast(bf16x8, t);
}

__device__ __forceinline__ float fexp2(float x) {
#if __has_builtin(__builtin_amdgcn_exp2f)
  return __builtin_amdgcn_exp2f(x);
#else
  return __builtin_exp2f(x);
#endif
}

// packed f32x2 -> bf16x2 (RNE), one VALU op
__device__ __forceinline__ unsigned cvtpk(float lo, float hi) {
  unsigned r;
  asm("v_cvt_pk_bf16_f32 %0, %1, %2" : "=v"(r) : "v"(lo), "v"(hi));
  return r;
}

// ---------------------------------------------------------------- kernel 1
__global__ void cvt_kernel(const float* __restrict__ Wq,
                           const float* __restrict__ Wk,
                           const float* __restrict__ Wv,
                           unsigned short* __restrict__ dst)
{
  const int idx = blockIdx.x * 256 + threadIdx.x;   // 0..196607
  const float* src = (idx < 65536) ? Wq : ((idx < 131072) ? Wk : Wv);
  dst[idx] = f2bf(src[idx & 65535]);
}

// ---------------------------------------------------------------- kernel 2
// Single pass per (b, pos-tile): x staged once (coalesced), 3 selectors x
// 4 o-strips from register-resident W. q pre-scaled by log2(e).
__global__ __launch_bounds__(256, 3)
void qkv_kernel(const float* __restrict__ x,
                const unsigned short* __restrict__ Wall,
                const float* __restrict__ bq,
                const float* __restrict__ bk,
                const float* __restrict__ bv,
                unsigned short* __restrict__ qT,
                unsigned short* __restrict__ kT,
                unsigned short* __restrict__ vG)
{
  __shared__ __align__(16) unsigned short xT[64 * 264];   // 33792 B
  __shared__ __align__(16) unsigned short tbuf[64 * 72];  //  9216 B

  const int b   = blockIdx.x;
  const int i0  = blockIdx.y * 64;
  const int tid = threadIdx.x;
  const int w   = tid >> 6;
  const int l   = tid & 63;
  const int n   = l & 15;
  const int q4  = l >> 4;

  {
    const int li = tid & 15;
    const int cg = tid >> 4;
#pragma unroll
    for (int it = 0; it < 16; ++it) {
      const int c = it * 16 + cg;
      f32x4 f = *reinterpret_cast<const f32x4*>(x + ((size_t)b * CCH + c) * NPOS + i0 + li * 4);
#pragma unroll
      for (int e = 0; e < 4; ++e) xT[(li * 4 + e) * 264 + c] = f2bf(f[e]);
    }
  }
  __syncthreads();

  const size_t qbase = (size_t)b * NPOS * CCH;
  bool first = true;

  for (int s = 0; s < 3; ++s) {
    const float* bias = (s == 0) ? bq : (s == 1) ? bk : bv;
    for (int op = 0; op < 4; ++op) {
      const int obase = op * 64;

      const unsigned short* Wp = Wall + s * 65536 + (size_t)(obase + w * 16 + n) * CCH + q4 * 8;
      bf16x8 wfr[8];
#pragma unroll
      for (int kk = 0; kk < 8; ++kk) wfr[kk] = ld_bf8(Wp + kk * 32);

      float bo[4];
#pragma unroll
      for (int r = 0; r < 4; ++r) bo[r] = bias[obase + w * 16 + q4 * 4 + r];

      f32x4 acc[4];
#pragma unroll
      for (int pt = 0; pt < 4; ++pt) {
        acc[pt] = {0.f, 0.f, 0.f, 0.f};
#pragma unroll
        for (int kk = 0; kk < 8; ++kk) {
          bf16x8 bfr = ld_bf8(&xT[(pt * 16 + n) * 264 + kk * 32 + q4 * 8]);
          acc[pt] = __builtin_amdgcn_mfma_f32_16x16x32_bf16(wfr[kk], bfr, acc[pt], 0, 0, 0);
        }
      }

      if (!first) __syncthreads();
      first = false;
      if (s < 2) {
        const float sc = (s == 0) ? LOG2E : 1.0f;
#pragma unroll
        for (int pt = 0; pt < 4; ++pt)
#pragma unroll
          for (int r = 0; r < 4; ++r)
            tbuf[(pt * 16 + n) * 72 + w * 16 + q4 * 4 + r] = f2bf((acc[pt][r] + bo[r]) * sc);
      } else {
#pragma unroll
        for (int pt = 0; pt < 4; ++pt)
#pragma unroll
          for (int r = 0; r < 4; ++r)
            tbuf[(w * 16 + q4 * 4 + r) * 72 + pt * 16 + n] = f2bf(acc[pt][r] + bo[r]);
      }
      __syncthreads();

      if (s < 2) {
        unsigned short* dst = (s == 0 ? qT : kT) + qbase;
#pragma unroll
        for (int it2 = 0; it2 < 2; ++it2) {
          const int idx = it2 * 256 + tid;
          const int pos = idx >> 3, ow = (idx & 7) * 8;
          i32x4 d = *reinterpret_cast<const i32x4*>(&tbuf[pos * 72 + ow]);
          *reinterpret_cast<i32x4*>(&dst[(size_t)(i0 + pos) * CCH + obase + ow]) = d;
        }
      } else {
#pragma unroll
        for (int it2 = 0; it2 < 2; ++it2) {
          const int idx = it2 * 256 + tid;
          const int o = idx >> 3, pw2 = (idx & 7) * 8;
          i32x4 d = *reinterpret_cast<const i32x4*>(&tbuf[o * 72 + pw2]);
          *reinterpret_cast<i32x4*>(&vG[qbase + (size_t)(obase + o) * NPOS + i0 + pw2]) = d;
        }
      }
    }
  }
}

// ---------------------------------------------------------------- kernel 3
// Flash attention = r7 (S^T swap) + lagging-max softmax + rescale-skip +
// setprio. r8 BUGFIX: the rescale pending from the FINAL iteration (acarry)
// was never applied to O -> fold it into the epilogue normalization:
// out = x + g*(acarry*O)/lrow, i.e. stat = acarry/lrow, sc = g*stat.
__global__ __launch_bounds__(256, 2)
void attn_kernel(const unsigned short* __restrict__ qT,
                 const unsigned short* __restrict__ kT,
                 const unsigned short* __restrict__ vG,
                 const float* __restrict__ x,
                 const float* __restrict__ gamma,
                 float* __restrict__ out)
{
  __shared__ __align__(16) unsigned short kbuf[2][64 * 256];  // 2 x 32768 B, swizzled
  __shared__ __align__(16) unsigned short pbuf[64 * 64];      //  8192 B, swizzled
  __shared__ float stat_lds[64];

  const int b   = blockIdx.x;
  const int i0  = blockIdx.y * 64;
  const int tid = threadIdx.x;
  const int w   = tid >> 6;
  const int l   = tid & 63;
  const int n   = l & 15;
  const int q4  = l >> 4;
  const int nsw = n & 7;

  const unsigned short* qTb = qT + (size_t)b * NPOS * CCH;
  const unsigned short* kTb = kT + (size_t)b * NPOS * CCH;
  const unsigned short* vb  = vG + (size_t)b * NPOS * CCH;

  // Q fragments register-resident (pre-scaled by log2e). Used as B operand:
  // lane holds Q[i = i0 + w*16 + n][ch = kk*32 + q4*8 + e]
  bf16x8 afr[8];
  {
    const unsigned short* qrow = qTb + (size_t)(i0 + w * 16 + n) * CCH + q4 * 8;
#pragma unroll
    for (int kk = 0; kk < 8; ++kk)
      afr[kk] = ld_bf8(qrow + kk * 32);
  }

  // stage K[0]: wave issues 8 DMA loads, instruction t covers local rows 2t,2t+1.
  // LDS granule (j,gp) holds logical granule g = gp ^ (j&7)  (bank-spread swizzle).
  {
#pragma unroll
    for (int it = 0; it < 8; ++it) {
      const int t = w * 8 + it;
      const int j = 2 * t + (l >> 5);
      const int gp = l & 31;
      const int g  = gp ^ (j & 7);
      const unsigned short* src = kTb + (size_t)j * CCH + g * 8;
      unsigned short* dst = &kbuf[0][t * 512];    // wave-uniform base
      __builtin_amdgcn_global_load_lds((GAS*)src, (LAS*)dst, 16, 0, 0);
    }
  }

  f32x4 O[16];   // [ct*4+it]: c in [w*64+ct*16,+16), i in [it*16,+16)
#pragma unroll
  for (int t = 0; t < 16; ++t) O[t] = {0.f, 0.f, 0.f, 0.f};
  float mcur = 64.f;    // lagging exp2-domain max for i = i0 + w*16 + n
  float lrow = 0.f;     // row sum at mcur scale (replicated across q4)
  float acarry = 1.0f;  // rescale factor decided at end of previous iter

  for (int jt = 0; jt < 64; ++jt) {
    const int j0 = jt * 64;
    const unsigned short* kb = kbuf[jt & 1];

    // prefetch V[jt] into registers (always the 8 NEWEST vmem ops)
    i32x4 vreg[8];
#pragma unroll
    for (int ct = 0; ct < 4; ++ct) {
      const unsigned short* vp = vb + (size_t)(w * 64 + ct * 16 + n) * NPOS + j0 + q4 * 8;
      vreg[ct * 2]     = *reinterpret_cast<const i32x4*>(vp);
      vreg[ct * 2 + 1] = *reinterpret_cast<const i32x4*>(vp + 32);
    }

    WAIT_VM8();     // drain everything older than V[jt] => K[jt] DMA complete
    BAR_RAW();      // all waves' K[jt] in LDS; pbuf/stat free (readers done pre-barrier)

    // S^T = K * Q: A = K (LDS, swizzled), B = Q regs.
    // D: lane holds S^T[j = nt*16 + q4*4 + r][i = n]
    f32x4 sacc[4];
    __builtin_amdgcn_s_setprio(1);
#pragma unroll
    for (int nt = 0; nt < 4; ++nt) {
      const unsigned short* krow = kb + (nt * 16 + n) * 256;
      sacc[nt] = {0.f, 0.f, 0.f, 0.f};
#pragma unroll
      for (int kk = 0; kk < 8; ++kk) {
        const int gp = (kk * 4 + q4) ^ nsw;
        bf16x8 bfr = ld_bf8(krow + gp * 8);
        sacc[nt] = __builtin_amdgcn_mfma_f32_16x16x32_bf16(bfr, afr[kk], sacc[nt], 0, 0, 0);
      }
    }
    __builtin_amdgcn_s_setprio(0);

    // local max tree (kept for the update check; off the exp critical path)
    float tml;
    {
      float a0 = fmaxf(fmaxf(sacc[0][0], sacc[0][1]), fmaxf(sacc[0][2], sacc[0][3]));
      float a1 = fmaxf(fmaxf(sacc[1][0], sacc[1][1]), fmaxf(sacc[1][2], sacc[1][3]));
      float a2 = fmaxf(fmaxf(sacc[2][0], sacc[2][1]), fmaxf(sacc[2][2], sacc[2][3]));
      float a3 = fmaxf(fmaxf(sacc[3][0], sacc[3][1]), fmaxf(sacc[3][2], sacc[3][3]));
      tml = fmaxf(fmaxf(a0, a1), fmaxf(a2, a3));
    }

    // P = exp2(S - mcur), lagging scale: starts immediately, no max wait
    float s = 0.f;
#pragma unroll
    for (int nt = 0; nt < 4; ++nt) {
#pragma unroll
      for (int r = 0; r < 4; ++r) {
        const float p = fexp2(sacc[nt][r] - mcur);
        sacc[nt][r] = p;
        s += p;
      }
    }

    // P -> pbuf row i = w*16+n: j pairs packed, 4 x ds_write_b64.
    // u16 slot j, granule = j/8, phys = granule ^ (row&7) = granule ^ nsw.
    {
      const int rowb = (w * 16 + n) * 64;
#pragma unroll
      for (int nt = 0; nt < 4; ++nt) {
        const unsigned lo = cvtpk(sacc[nt][0], sacc[nt][1]);
        const unsigned hi = cvtpk(sacc[nt][2], sacc[nt][3]);
        const int pg = (2 * nt + (q4 >> 1)) ^ nsw;
        i32x2 dv = { (int)lo, (int)hi };
        *reinterpret_cast<i32x2*>(&pbuf[rowb + pg * 8 + (q4 & 1) * 4]) = dv;
      }
    }
    if (q4 == 0) stat_lds[w * 16 + n] = acarry;   // rescale decided last iter

    // reductions off critical path
    s += __shfl_xor(s, 16);
    s += __shfl_xor(s, 32);
    lrow += s;
    float tm = fmaxf(tml, __shfl_xor(tml, 16));
    tm = fmaxf(tm, __shfl_xor(tm, 32));

    // prefetch K[jt+1] DMA into other buffer (UNCONDITIONAL, wrapped: keeps
    // compiler's V-use wait at vmcnt(8) instead of vmcnt(0))
    {
      const int j0n = ((jt + 1) & 63) * 64;
      unsigned short* bufn = kbuf[(jt + 1) & 1];
#pragma unroll
      for (int it = 0; it < 8; ++it) {
        const int t = w * 8 + it;
        const int j = 2 * t + (l >> 5);
        const int gp = l & 31;
        const int g  = gp ^ (j & 7);
        const unsigned short* src = kTb + (size_t)(j0n + j) * CCH + g * 8;
        unsigned short* dst = &bufn[t * 512];
        __builtin_amdgcn_global_load_lds((GAS*)src, (LAS*)dst, 16, 0, 0);
      }
    }

    WAIT_LGKM0();   // my P/alpha writes landed
    BAR_RAW();      // P + alpha visible to all; K' DMA still in flight

    // rescale O by alpha[i] — skipped when no wave updated last iter
    {
      const float al0 = stat_lds[n];
      const float al1 = stat_lds[16 + n];
      const float al2 = stat_lds[32 + n];
      const float al3 = stat_lds[48 + n];
      if (al0 + al1 + al2 + al3 != 4.0f) {
        const float als[4] = { al0, al1, al2, al3 };
#pragma unroll
        for (int it = 0; it < 4; ++it) {
          const float al = als[it];
#pragma unroll
          for (int ct = 0; ct < 4; ++ct) {
            f32x4& o = O[ct * 4 + it];
            o[0] *= al; o[1] *= al; o[2] *= al; o[3] *= al;
          }
        }
      }
    }

    // PV: V from registers, P from swizzled LDS
    bf16x8 pf[8];
#pragma unroll
    for (int it = 0; it < 4; ++it) {
      const int rowb = (it * 16 + n) * 64;
      pf[it * 2 + 0] = ld_bf8(&pbuf[rowb + ((q4 ^ nsw) << 3)]);
      pf[it * 2 + 1] = ld_bf8(&pbuf[rowb + (((4 + q4) ^ nsw) << 3)]);
    }
    __builtin_amdgcn_s_setprio(1);
#pragma unroll
    for (int ct = 0; ct < 4; ++ct) {
      bf16x8 vf0 = __builtin_bit_cast(bf16x8, vreg[ct * 2]);
      bf16x8 vf1 = __builtin_bit_cast(bf16x8, vreg[ct * 2 + 1]);
#pragma unroll
      for (int it = 0; it < 4; ++it) {
        O[ct * 4 + it] = __builtin_amdgcn_mfma_f32_16x16x32_bf16(vf0, pf[it * 2 + 0], O[ct * 4 + it], 0, 0, 0);
        O[ct * 4 + it] = __builtin_amdgcn_mfma_f32_16x16x32_bf16(vf1, pf[it * 2 + 1], O[ct * 4 + it], 0, 0, 0);
      }
    }
    __builtin_amdgcn_s_setprio(0);

    // deferred max update (rare): threshold 8 bounds P <= 2^8 between updates
    const int upd = tm > mcur + 8.f;
    if (__any(upd)) {
      const float mn = upd ? tm : mcur;
      const float al = fexp2(mcur - mn);
      mcur = mn;
      lrow *= al;
      acarry = al;
    } else {
      acarry = 1.0f;
    }
  }

  // epilogue: out = x + g*(acarry*O)/lrow — acarry folds in the final
  // iteration's pending O-rescale (the r8 bug: it was dropped).
  __syncthreads();
  if (q4 == 0) stat_lds[w * 16 + n] = acarry / lrow;
  __syncthreads();

  const float g = gamma[0];
#pragma unroll
  for (int it = 0; it < 4; ++it) {
    const float sc = g * stat_lds[it * 16 + n];
    const int ipos = i0 + it * 16 + n;
#pragma unroll
    for (int ct = 0; ct < 4; ++ct) {
#pragma unroll
      for (int r = 0; r < 4; ++r) {
        const int c = w * 64 + ct * 16 + q4 * 4 + r;
        const size_t idx = ((size_t)(b * CCH + c)) * NPOS + ipos;
        out[idx] = x[idx] + sc * O[ct * 4 + it][r];
      }
    }
  }
}

// ---------------------------------------------------------------- launch
extern "C" void kernel_launch(void* const* d_in, const int* in_sizes, int n_in,
                              void* d_out, int out_size, void* d_ws, size_t ws_size,
                              hipStream_t stream)
{
  const float* x     = (const float*)d_in[0];
  const float* Wq    = (const float*)d_in[1];
  const float* bq    = (const float*)d_in[2];
  const float* Wk    = (const float*)d_in[3];
  const float* bk    = (const float*)d_in[4];
  const float* Wv    = (const float*)d_in[5];
  const float* bv    = (const float*)d_in[6];
  const float* gamma = (const float*)d_in[7];
  float* out = (float*)d_out;

  unsigned short* ws   = (unsigned short*)d_ws;
  unsigned short* Wall = ws;                                  // 3 x 65536 bf16
  unsigned short* qT   = ws + 196608;                         // (B,N,C) bf16, pre-scaled log2e
  unsigned short* kT   = qT + (size_t)BATCH * NPOS * CCH;     // (B,N,C) bf16
  unsigned short* vG   = kT + (size_t)BATCH * NPOS * CCH;     // (B,C,N) bf16

  cvt_kernel<<<768, 256, 0, stream>>>(Wq, Wk, Wv, Wall);
  qkv_kernel<<<dim3(8, 64), 256, 0, stream>>>(x, Wall, bq, bk, bv, qT, kT, vG);
  attn_kernel<<<dim3(8, 64), 256, 0, stream>>>(qT, kT, vG, x, gamma, out);
}